// Round 2
// baseline (852.598 us; speedup 1.0000x reference)
//
#include <hip/hip_runtime.h>
#include <hip/hip_bf16.h>

// GraphSAGE backbone: 2x SAGEConv(mean), N=100000, E=1600000, D=128, fp32.
// Pipeline: CSR build (degree -> scan -> scatter), then per layer:
//   agg = mean gather; tmp = agg@Wl + b (in-place over agg); out = relu(h@Wr + tmp)
// NOTE: harness passes integer inputs as int32 (edge_index -> const int*).

#define D 128

// ---- CSR build ------------------------------------------------------------

__global__ __launch_bounds__(256) void k_degree(const int* __restrict__ ei,
                                                int E, int* __restrict__ cnt) {
  int e = blockIdx.x * blockDim.x + threadIdx.x;
  if (e < E) atomicAdd(&cnt[ei[E + e]], 1);
}

// single-block exclusive scan over cnt[0..n) -> rowptr, plus inv_denom
__global__ __launch_bounds__(1024) void k_scan(const int* __restrict__ cnt, int n,
                                               int* __restrict__ rowptr,
                                               float* __restrict__ inv_denom) {
  __shared__ int wsum[17];
  int tid = threadIdx.x, lane = tid & 63, wid = tid >> 6;
  int running = 0;
  for (int base = 0; base < n; base += 1024) {
    int i = base + tid;
    int v = (i < n) ? cnt[i] : 0;
    int x = v;
#pragma unroll
    for (int off = 1; off < 64; off <<= 1) {
      int t = __shfl_up(x, (unsigned)off);
      if (lane >= off) x += t;
    }
    if (lane == 63) wsum[wid] = x;
    __syncthreads();
    if (tid == 0) {
      int acc = 0;
#pragma unroll
      for (int j = 0; j < 16; ++j) { int t = wsum[j]; wsum[j] = acc; acc += t; }
      wsum[16] = acc;
    }
    __syncthreads();
    if (i < n) {
      rowptr[i] = running + wsum[wid] + x - v;   // exclusive
      inv_denom[i] = 1.0f / (float)((v > 1) ? v : 1);
    }
    running += wsum[16];
    __syncthreads();   // protect wsum before next iteration
  }
  if (tid == 0) rowptr[n] = running;
}

__global__ __launch_bounds__(256) void k_scatter(const int* __restrict__ ei,
                                                 int E, const int* __restrict__ rowptr,
                                                 int* __restrict__ fill,
                                                 int* __restrict__ csr) {
  int e = blockIdx.x * blockDim.x + threadIdx.x;
  if (e < E) {
    int s = ei[e];
    int d = ei[E + e];
    int pos = rowptr[d] + atomicAdd(&fill[d], 1);
    csr[pos] = s;
  }
}

// ---- mean aggregation: one wave per node ----------------------------------

__global__ __launch_bounds__(256) void k_agg(const float* __restrict__ h,
                                             const int* __restrict__ rowptr,
                                             const int* __restrict__ csr,
                                             const float* __restrict__ inv_denom,
                                             float* __restrict__ agg, int n) {
  int gw = (int)((blockIdx.x * (unsigned)blockDim.x + threadIdx.x) >> 6);
  int lane = threadIdx.x & 63;
  if (gw >= n) return;
  int beg = __builtin_amdgcn_readfirstlane(rowptr[gw]);
  int end = __builtin_amdgcn_readfirstlane(rowptr[gw + 1]);
  float ax0 = 0.f, ay0 = 0.f, ax1 = 0.f, ay1 = 0.f;
  float ax2 = 0.f, ay2 = 0.f, ax3 = 0.f, ay3 = 0.f;
  int e = beg;
  for (; e + 4 <= end; e += 4) {           // 4 gathers in flight
    int s0 = csr[e], s1 = csr[e + 1], s2 = csr[e + 2], s3 = csr[e + 3];
    float2 v0 = ((const float2*)(h + (size_t)s0 * D))[lane];
    float2 v1 = ((const float2*)(h + (size_t)s1 * D))[lane];
    float2 v2 = ((const float2*)(h + (size_t)s2 * D))[lane];
    float2 v3 = ((const float2*)(h + (size_t)s3 * D))[lane];
    ax0 += v0.x; ay0 += v0.y; ax1 += v1.x; ay1 += v1.y;
    ax2 += v2.x; ay2 += v2.y; ax3 += v3.x; ay3 += v3.y;
  }
  for (; e < end; ++e) {
    int s = csr[e];
    float2 v = ((const float2*)(h + (size_t)s * D))[lane];
    ax0 += v.x; ay0 += v.y;
  }
  float iv = inv_denom[gw];
  float2 r;
  r.x = (ax0 + ax1 + ax2 + ax3) * iv;
  r.y = (ay0 + ay1 + ay2 + ay3) * iv;
  ((float2*)(agg + (size_t)gw * D))[lane] = r;
}

// ---- fp32 GEMM: out = [relu]( A @ W [+ bias] [+ addend] ) ------------------
// W (128x128) staged in LDS. One wave computes an 8-row x 128-col tile:
// lane owns 2 output cols; A-row values broadcast via v_readlane.
// NOTE: A/addend/out may alias (in-place per-row) -> no __restrict__ on them.

__global__ __launch_bounds__(512) void k_gemm(const float* A,
                                              const float* __restrict__ W,
                                              const float* __restrict__ bias,
                                              const float* addend,
                                              float* out, int n, int relu) {
  __shared__ float Wlds[D * D];   // 64 KB
  int tid = threadIdx.x;
  for (int i = tid; i < D * D / 4; i += 512)
    ((float4*)Wlds)[i] = ((const float4*)W)[i];
  __syncthreads();

  int lane = tid & 63, wid = tid >> 6;
  int nt = (n + 7) >> 3;
  int gw0 = blockIdx.x * 8 + wid;
  int stride = gridDim.x * 8;

  float2 bv = {0.f, 0.f};
  if (bias) bv = ((const float2*)bias)[lane];

  for (int tile = gw0; tile < nt; tile += stride) {
    int r0 = tile * 8;
    float2 a[8], acc[8];
#pragma unroll
    for (int j = 0; j < 8; ++j) {
      int r = r0 + j;
      if (r < n) a[j] = ((const float2*)(A + (size_t)r * D))[lane];
      else { a[j].x = 0.f; a[j].y = 0.f; }
      acc[j] = bv;
    }
    for (int k0 = 0; k0 < D; k0 += 16) {
#pragma unroll
      for (int kk = 0; kk < 16; ++kk) {
        float2 w = ((const float2*)(Wlds + (k0 + kk) * D))[lane];
#pragma unroll
        for (int j = 0; j < 8; ++j) {
          int bits = __builtin_amdgcn_readlane(
              __float_as_int((kk & 1) ? a[j].y : a[j].x), (k0 + kk) >> 1);
          float ak = __int_as_float(bits);
          acc[j].x = fmaf(ak, w.x, acc[j].x);
          acc[j].y = fmaf(ak, w.y, acc[j].y);
        }
      }
    }
#pragma unroll
    for (int j = 0; j < 8; ++j) {
      int r = r0 + j;
      if (r >= n) continue;
      float2 o = acc[j];
      if (addend) {
        float2 c = ((const float2*)(addend + (size_t)r * D))[lane];
        o.x += c.x; o.y += c.y;
      }
      if (relu) { o.x = o.x > 0.f ? o.x : 0.f; o.y = o.y > 0.f ? o.y : 0.f; }
      ((float2*)(out + (size_t)r * D))[lane] = o;
    }
  }
}

// ---- launch ----------------------------------------------------------------

extern "C" void kernel_launch(void* const* d_in, const int* in_sizes, int n_in,
                              void* d_out, int out_size, void* d_ws, size_t ws_size,
                              hipStream_t stream) {
  const float* x = (const float*)d_in[0];
  const int* ei = (const int*)d_in[1];   // int inputs arrive as int32
  const float* Wl0 = (const float*)d_in[2];
  const float* Wr0 = (const float*)d_in[3];
  const float* b0  = (const float*)d_in[4];
  const float* Wl1 = (const float*)d_in[5];
  const float* Wr1 = (const float*)d_in[6];
  const float* b1  = (const float*)d_in[7];
  const int N = in_sizes[0] / D;
  const int E = in_sizes[1] / 2;
  float* out = (float*)d_out;

  // workspace layout (~59 MB): cnt | fill | rowptr | inv_denom | csr | aggbuf
  size_t NP = ((size_t)N + 64) & ~(size_t)63;   // >= N+1, aligned
  size_t EP = ((size_t)E + 63) & ~(size_t)63;
  int*   cnt    = (int*)d_ws;
  int*   fill   = cnt + NP;
  int*   rowptr = fill + NP;
  float* inv    = (float*)(rowptr + NP);
  int*   csr    = (int*)(inv + NP);
  float* aggb   = (float*)(csr + EP);

  hipMemsetAsync(cnt, 0, NP * sizeof(int), stream);
  hipMemsetAsync(fill, 0, NP * sizeof(int), stream);

  int egrid = (E + 255) / 256;
  k_degree<<<egrid, 256, 0, stream>>>(ei, E, cnt);
  k_scan<<<1, 1024, 0, stream>>>(cnt, N, rowptr, inv);
  k_scatter<<<egrid, 256, 0, stream>>>(ei, E, rowptr, fill, csr);

  int agrid = (N + 3) / 4;   // 4 waves/block, 1 wave/node

  // layer 0: h0 -> d_out
  k_agg<<<agrid, 256, 0, stream>>>(x, rowptr, csr, inv, aggb, N);
  k_gemm<<<512, 512, 0, stream>>>(aggb, Wl0, b0, nullptr, aggb, N, 0);
  k_gemm<<<512, 512, 0, stream>>>(x, Wr0, nullptr, aggb, out, N, 1);

  // layer 1: out -> d_out (in-place per-row is safe: each wave reads its
  // rows into registers before writing them)
  k_agg<<<agrid, 256, 0, stream>>>(out, rowptr, csr, inv, aggb, N);
  k_gemm<<<512, 512, 0, stream>>>(aggb, Wl1, b1, nullptr, aggb, N, 0);
  k_gemm<<<512, 512, 0, stream>>>(out, Wr1, nullptr, aggb, out, N, 1);
}

// Round 3
// 556.960 us; speedup vs baseline: 1.5308x; 1.5308x over previous
//
#include <hip/hip_runtime.h>
#include <hip/hip_bf16.h>

// GraphSAGE backbone: 2x SAGEConv(mean), N=100000, E=1600000, D=128, fp32 in/out.
// CSR build (degree -> hierarchical scan -> scatter), per layer:
//   agg = mean gather (wave per node);  out = relu(agg@Wl + h@Wr + b) fused
//   bf16 MFMA GEMM (weights bf16-transposed in LDS, fp32 accumulate).

#define D 128
#define WSTRIDE 136            // 128 + 8 bf16 pad -> <=2-way LDS bank aliasing
#define WPANEL (D * WSTRIDE)   // shorts per weight panel

typedef __attribute__((ext_vector_type(8))) short short8v;
typedef __attribute__((ext_vector_type(4))) float f32x4;

__device__ inline short f2bf(float f) {   // fp32 -> bf16 RNE
  unsigned u = __float_as_uint(f);
  unsigned r = (u + 0x7FFFu + ((u >> 16) & 1u)) >> 16;
  return (short)r;
}

// ---- CSR build ------------------------------------------------------------

__global__ __launch_bounds__(256) void k_degree(const int* __restrict__ ei,
                                                int E, int* __restrict__ cnt) {
  int e = blockIdx.x * blockDim.x + threadIdx.x;
  if (e < E) atomicAdd(&cnt[ei[E + e]], 1);
}

// per-block local exclusive scan (1024 elems) + block sums + inv_denom
__global__ __launch_bounds__(1024) void k_scan1(const int* __restrict__ cnt, int n,
                                                int* __restrict__ rowptr,
                                                float* __restrict__ inv_denom,
                                                int* __restrict__ bsum) {
  __shared__ int wsum[16];
  int tid = threadIdx.x, lane = tid & 63, wid = tid >> 6;
  int i = blockIdx.x * 1024 + tid;
  int v = (i < n) ? cnt[i] : 0;
  int x = v;
#pragma unroll
  for (int off = 1; off < 64; off <<= 1) {
    int t = __shfl_up(x, (unsigned)off);
    if (lane >= off) x += t;
  }
  if (lane == 63) wsum[wid] = x;
  __syncthreads();
  if (tid < 16) {
    int w = wsum[tid], y = w;
#pragma unroll
    for (int off = 1; off < 16; off <<= 1) {
      int t = __shfl_up(y, (unsigned)off);
      if (tid >= off) y += t;
    }
    wsum[tid] = y - w;   // exclusive
  }
  __syncthreads();
  if (i < n) {
    rowptr[i] = wsum[wid] + x - v;               // block-local exclusive
    inv_denom[i] = 1.0f / (float)((v > 1) ? v : 1);
  }
  if (tid == 1023) bsum[blockIdx.x] = wsum[15] + x;  // block total
}

// single-wave scan of block sums (nb <= 128); writes rowptr[n] = grand total
__global__ __launch_bounds__(64) void k_scan2(int* __restrict__ bsum, int nb,
                                              int* __restrict__ rowptr, int n) {
  int lane = threadIdx.x;
  int v0 = (lane < nb) ? bsum[lane] : 0;
  int v1 = (64 + lane < nb) ? bsum[64 + lane] : 0;
  int x = v0;
#pragma unroll
  for (int off = 1; off < 64; off <<= 1) {
    int t = __shfl_up(x, (unsigned)off);
    if (lane >= off) x += t;
  }
  int tot0 = __shfl(x, 63);
  int y = v1;
#pragma unroll
  for (int off = 1; off < 64; off <<= 1) {
    int t = __shfl_up(y, (unsigned)off);
    if (lane >= off) y += t;
  }
  if (lane < nb) bsum[lane] = x - v0;
  if (64 + lane < nb) bsum[64 + lane] = tot0 + (y - v1);
  if (lane == 63) rowptr[n] = tot0 + y;
}

__global__ __launch_bounds__(1024) void k_scan3(int* __restrict__ rowptr,
                                                const int* __restrict__ bsum, int n) {
  int i = blockIdx.x * 1024 + threadIdx.x;
  if (i < n) rowptr[i] += bsum[blockIdx.x];
}

__global__ __launch_bounds__(256) void k_scatter(const int* __restrict__ ei,
                                                 int E, const int* __restrict__ rowptr,
                                                 int* __restrict__ fill,
                                                 int* __restrict__ csr) {
  int e = blockIdx.x * blockDim.x + threadIdx.x;
  if (e < E) {
    int s = ei[e];
    int d = ei[E + e];
    int pos = rowptr[d] + atomicAdd(&fill[d], 1);
    csr[pos] = s;
  }
}

// ---- weight prep: fp32 row-major W[k][c] -> bf16 transposed WT[c][k] -------

__global__ __launch_bounds__(256) void k_wprep(const float* __restrict__ W0,
                                               const float* __restrict__ W1,
                                               const float* __restrict__ W2,
                                               const float* __restrict__ W3,
                                               short* __restrict__ WT) {
  const float* W = (blockIdx.y == 0) ? W0 : (blockIdx.y == 1) ? W1
                 : (blockIdx.y == 2) ? W2 : W3;
  short* o = WT + (size_t)blockIdx.y * WPANEL;
  int i = blockIdx.x * 256 + threadIdx.x;
  if (i < D * D) {
    int k = i >> 7, c = i & 127;
    o[c * WSTRIDE + k] = f2bf(W[i]);
  }
}

// ---- mean aggregation: one wave per node, float4, 2 edges per half-wave ----

__global__ __launch_bounds__(256) void k_agg(const float* __restrict__ h,
                                             const int* __restrict__ rowptr,
                                             const int* __restrict__ csr,
                                             const float* __restrict__ inv_denom,
                                             float* __restrict__ agg, int n) {
  int gw = (int)((blockIdx.x * (unsigned)blockDim.x + threadIdx.x) >> 6);
  if (gw >= n) return;
  int lane = threadIdx.x & 63;
  int half = lane >> 5, sub = lane & 31;
  int beg = __builtin_amdgcn_readfirstlane(rowptr[gw]);
  int end = __builtin_amdgcn_readfirstlane(rowptr[gw + 1]);
  float sx0 = 0.f, sy0 = 0.f, sz0 = 0.f, sw0 = 0.f;
  float sx1 = 0.f, sy1 = 0.f, sz1 = 0.f, sw1 = 0.f;
  int e = beg;
  for (; e + 4 <= end; e += 4) {
    int i0 = csr[e + half];
    int i1 = csr[e + 2 + half];
    float4 v0 = ((const float4*)(h + (size_t)i0 * D))[sub];
    float4 v1 = ((const float4*)(h + (size_t)i1 * D))[sub];
    sx0 += v0.x; sy0 += v0.y; sz0 += v0.z; sw0 += v0.w;
    sx1 += v1.x; sy1 += v1.y; sz1 += v1.z; sw1 += v1.w;
  }
  if (e + 2 <= end) {
    int i0 = csr[e + half];
    float4 v0 = ((const float4*)(h + (size_t)i0 * D))[sub];
    sx0 += v0.x; sy0 += v0.y; sz0 += v0.z; sw0 += v0.w;
    e += 2;
  }
  if (e < end) {   // odd tail: half 0 only
    int i0 = csr[e];
    float4 v0 = ((const float4*)(h + (size_t)i0 * D))[sub];
    if (half == 0) { sx0 += v0.x; sy0 += v0.y; sz0 += v0.z; sw0 += v0.w; }
  }
  float sx = sx0 + sx1, sy = sy0 + sy1, sz = sz0 + sz1, sw = sw0 + sw1;
  sx += __shfl_xor(sx, 32);
  sy += __shfl_xor(sy, 32);
  sz += __shfl_xor(sz, 32);
  sw += __shfl_xor(sw, 32);
  if (half == 0) {
    float iv = inv_denom[gw];
    float4 r; r.x = sx * iv; r.y = sy * iv; r.z = sz * iv; r.w = sw * iv;
    ((float4*)(agg + (size_t)gw * D))[sub] = r;
  }
}

// ---- fused layer GEMM: out = relu(A@Wl + H@Wr + bias) ----------------------
// MFMA 16x16x32 bf16, fp32 accumulate. Wave owns a 16-row tile.
// A/H fragments: row = lane&15, k = 8*(lane>>4)+j (loaded from global fp32).
// B fragments from LDS WT[c][k] (bf16, stride 136).
// H may alias out (wave reads all its rows before writing them).

__global__ __launch_bounds__(512) void k_fgemm(const float* A, const float* H,
                                               const short* __restrict__ WTl,
                                               const short* __restrict__ WTr,
                                               const float* __restrict__ bias,
                                               float* out, int n) {
  __shared__ short wl[WPANEL];
  __shared__ short wr[WPANEL];
  int tid = threadIdx.x;
  for (int i = tid; i < WPANEL / 8; i += 512) {
    ((int4*)wl)[i] = ((const int4*)WTl)[i];
    ((int4*)wr)[i] = ((const int4*)WTr)[i];
  }
  __syncthreads();

  int lane = tid & 63, wid = tid >> 6;
  int c = lane & 15, g = lane >> 4;
  float bv[8];
#pragma unroll
  for (int cc = 0; cc < 8; ++cc) bv[cc] = bias[cc * 16 + c];

  int ntile = (n + 15) >> 4;
  for (int tile = blockIdx.x * 8 + wid; tile < ntile; tile += gridDim.x * 8) {
    int r0 = tile * 16;
    int row = r0 + c;
    bool rok = row < n;
    f32x4 acc[8];
#pragma unroll
    for (int cc = 0; cc < 8; ++cc) acc[cc] = (f32x4){0.f, 0.f, 0.f, 0.f};

#pragma unroll
    for (int t = 0; t < 4; ++t) {
      short8v af = (short8v){0,0,0,0,0,0,0,0};
      short8v hf = (short8v){0,0,0,0,0,0,0,0};
      if (rok) {
        const float4* pa = (const float4*)(A + (size_t)row * D + t * 32 + g * 8);
        float4 a0 = pa[0], a1 = pa[1];
        const float4* ph = (const float4*)(H + (size_t)row * D + t * 32 + g * 8);
        float4 h0 = ph[0], h1 = ph[1];
        af[0] = f2bf(a0.x); af[1] = f2bf(a0.y); af[2] = f2bf(a0.z); af[3] = f2bf(a0.w);
        af[4] = f2bf(a1.x); af[5] = f2bf(a1.y); af[6] = f2bf(a1.z); af[7] = f2bf(a1.w);
        hf[0] = f2bf(h0.x); hf[1] = f2bf(h0.y); hf[2] = f2bf(h0.z); hf[3] = f2bf(h0.w);
        hf[4] = f2bf(h1.x); hf[5] = f2bf(h1.y); hf[6] = f2bf(h1.z); hf[7] = f2bf(h1.w);
      }
      int kb = t * 32 + g * 8;
#pragma unroll
      for (int cc = 0; cc < 8; ++cc) {
        short8v bl = *(const short8v*)&wl[(cc * 16 + c) * WSTRIDE + kb];
        acc[cc] = __builtin_amdgcn_mfma_f32_16x16x32_bf16(af, bl, acc[cc], 0, 0, 0);
        short8v br = *(const short8v*)&wr[(cc * 16 + c) * WSTRIDE + kb];
        acc[cc] = __builtin_amdgcn_mfma_f32_16x16x32_bf16(hf, br, acc[cc], 0, 0, 0);
      }
    }
    // D[row' = g*4+i][col = cc*16+c]
#pragma unroll
    for (int cc = 0; cc < 8; ++cc) {
#pragma unroll
      for (int i = 0; i < 4; ++i) {
        int rr = r0 + g * 4 + i;
        if (rr < n) {
          float o = acc[cc][i] + bv[cc];
          out[(size_t)rr * D + cc * 16 + c] = o > 0.f ? o : 0.f;
        }
      }
    }
  }
}

// ---- launch ----------------------------------------------------------------

extern "C" void kernel_launch(void* const* d_in, const int* in_sizes, int n_in,
                              void* d_out, int out_size, void* d_ws, size_t ws_size,
                              hipStream_t stream) {
  const float* x   = (const float*)d_in[0];
  const int*   ei  = (const int*)d_in[1];   // int inputs arrive as int32
  const float* Wl0 = (const float*)d_in[2];
  const float* Wr0 = (const float*)d_in[3];
  const float* b0  = (const float*)d_in[4];
  const float* Wl1 = (const float*)d_in[5];
  const float* Wr1 = (const float*)d_in[6];
  const float* b1  = (const float*)d_in[7];
  const int N = in_sizes[0] / D;
  const int E = in_sizes[1] / 2;
  float* out = (float*)d_out;

  // ws layout (4B units): cnt | fill | rowptr | inv | bsum(1024) | csr | WT | aggb
  size_t NP = ((size_t)N + 64) & ~(size_t)63;
  size_t EP = ((size_t)E + 63) & ~(size_t)63;
  int*   cnt    = (int*)d_ws;
  int*   fill   = cnt + NP;
  int*   rowptr = fill + NP;
  float* inv    = (float*)(rowptr + NP);
  int*   bsum   = (int*)(inv + NP);
  int*   csr    = bsum + 1024;
  short* wt     = (short*)(csr + EP);          // 4 panels of WPANEL shorts
  float* aggb   = (float*)(csr + EP + (4 * WPANEL + 1) / 2);

  hipMemsetAsync(cnt, 0, NP * sizeof(int), stream);
  hipMemsetAsync(fill, 0, NP * sizeof(int), stream);

  int egrid = (E + 255) / 256;
  int NB = (N + 1023) / 1024;
  k_degree<<<egrid, 256, 0, stream>>>(ei, E, cnt);
  k_scan1<<<NB, 1024, 0, stream>>>(cnt, N, rowptr, inv, bsum);
  k_scan2<<<1, 64, 0, stream>>>(bsum, NB, rowptr, N);
  k_scan3<<<NB, 1024, 0, stream>>>(rowptr, bsum, N);
  k_scatter<<<egrid, 256, 0, stream>>>(ei, E, rowptr, fill, csr);

  dim3 wgrid((D * D + 255) / 256, 4);
  k_wprep<<<wgrid, 256, 0, stream>>>(Wl0, Wr0, Wl1, Wr1, wt);

  int agrid = (N + 3) / 4;   // 4 waves/block, 1 wave/node

  // layer 0
  k_agg<<<agrid, 256, 0, stream>>>(x, rowptr, csr, inv, aggb, N);
  k_fgemm<<<512, 512, 0, stream>>>(aggb, x, wt, wt + WPANEL, b0, out, N);

  // layer 1 (H aliases out; safe per-wave read-before-write)
  k_agg<<<agrid, 256, 0, stream>>>(out, rowptr, csr, inv, aggb, N);
  k_fgemm<<<512, 512, 0, stream>>>(aggb, out, wt + 2 * WPANEL, wt + 3 * WPANEL, b1, out, N);
}

// Round 4
// 319.425 us; speedup vs baseline: 2.6692x; 1.7436x over previous
//
#include <hip/hip_runtime.h>
#include <hip/hip_bf16.h>

// GraphSAGE backbone: 2x SAGEConv(mean), N=100000, E=1600000, D=128, fp32 in/out.
// CSR build via 2-pass bucket binning (no write-amplified scatter), then per layer:
//   agg = mean gather (bf16 rows, fp32 accum);  out = relu(agg@Wl + h@Wr + b)
//   fused bf16 MFMA GEMM. Intermediate h1 kept bf16-only.

#define D 128
#define WSTRIDE 136            // 128 + 8 bf16 pad
#define WPANEL (D * WSTRIDE)   // shorts per weight panel
#define GCAP 12288             // per-bucket capacity (mean 8192, +45 sigma)

typedef __attribute__((ext_vector_type(8))) short short8v;
typedef __attribute__((ext_vector_type(4))) float f32x4;

__device__ inline unsigned short f2bf(float f) {   // fp32 -> bf16 RNE
  unsigned u = __float_as_uint(f);
  return (unsigned short)((u + 0x7FFFu + ((u >> 16) & 1u)) >> 16);
}
__device__ inline unsigned pack2(float lo, float hi) {
  return (unsigned)f2bf(lo) | ((unsigned)f2bf(hi) << 16);
}

// ---- pass A: bin edges by dst>>9 into gbuf[b*GCAP + cursor] ---------------
// entry = (src<<9) | (dst&511); per-block LDS count -> 1 global atomic/bucket.

__global__ __launch_bounds__(256) void k_bin(const int* __restrict__ ei, int E,
                                             int* __restrict__ gcur,
                                             int* __restrict__ gbuf) {
  __shared__ int hcnt[256], hbase[256], hfill[256];
  int tid = threadIdx.x;
  hcnt[tid] = 0;
  __syncthreads();
  int ent[8], bk[8];
#pragma unroll
  for (int it = 0; it < 8; ++it) {
    int e = blockIdx.x * 2048 + it * 256 + tid;
    if (e < E) {
      int s = ei[e], d = ei[E + e];
      bk[it] = d >> 9;
      ent[it] = (s << 9) | (d & 511);
      atomicAdd(&hcnt[bk[it]], 1);
    } else bk[it] = -1;
  }
  __syncthreads();
  int c = hcnt[tid];
  hbase[tid] = c ? atomicAdd(&gcur[tid], c) : 0;
  hfill[tid] = 0;
  __syncthreads();
#pragma unroll
  for (int it = 0; it < 8; ++it) {
    if (bk[it] >= 0) {
      int slot = atomicAdd(&hfill[bk[it]], 1);
      gbuf[(size_t)bk[it] * GCAP + hbase[bk[it]] + slot] = ent[it];
    }
  }
}

// ---- pass B1: per-bucket degree histogram -> cnt (coalesced) ---------------

__global__ __launch_bounds__(256) void k_hist(const int* __restrict__ gcur,
                                              const int* __restrict__ gbuf,
                                              int* __restrict__ cnt, int n) {
  __shared__ int hc[512];
  int b = blockIdx.x, tid = threadIdx.x;
  hc[tid] = 0; hc[tid + 256] = 0;
  __syncthreads();
  int m = gcur[b];
  for (int i = tid; i < m; i += 256)
    atomicAdd(&hc[gbuf[(size_t)b * GCAP + i] & 511], 1);
  __syncthreads();
#pragma unroll
  for (int k = 0; k < 2; ++k) {
    int i = k * 256 + tid, node = b * 512 + i;
    if (node < n) cnt[node] = hc[i];
  }
}

// ---- hierarchical exclusive scan: cnt -> rowptr, plus inv_denom ------------

__global__ __launch_bounds__(1024) void k_scan1(const int* __restrict__ cnt, int n,
                                                int* __restrict__ rowptr,
                                                float* __restrict__ inv_denom,
                                                int* __restrict__ bsum) {
  __shared__ int wsum[16];
  int tid = threadIdx.x, lane = tid & 63, wid = tid >> 6;
  int i = blockIdx.x * 1024 + tid;
  int v = (i < n) ? cnt[i] : 0;
  int x = v;
#pragma unroll
  for (int off = 1; off < 64; off <<= 1) {
    int t = __shfl_up(x, (unsigned)off);
    if (lane >= off) x += t;
  }
  if (lane == 63) wsum[wid] = x;
  __syncthreads();
  if (tid < 16) {
    int w = wsum[tid], y = w;
#pragma unroll
    for (int off = 1; off < 16; off <<= 1) {
      int t = __shfl_up(y, (unsigned)off);
      if (tid >= off) y += t;
    }
    wsum[tid] = y - w;   // exclusive
  }
  __syncthreads();
  if (i < n) {
    rowptr[i] = wsum[wid] + x - v;
    inv_denom[i] = 1.0f / (float)((v > 1) ? v : 1);
  }
  if (tid == 1023) bsum[blockIdx.x] = wsum[15] + x;
}

__global__ __launch_bounds__(64) void k_scan2(int* __restrict__ bsum, int nb,
                                              int* __restrict__ rowptr, int n) {
  int lane = threadIdx.x;
  int v0 = (lane < nb) ? bsum[lane] : 0;
  int v1 = (64 + lane < nb) ? bsum[64 + lane] : 0;
  int x = v0;
#pragma unroll
  for (int off = 1; off < 64; off <<= 1) {
    int t = __shfl_up(x, (unsigned)off);
    if (lane >= off) x += t;
  }
  int tot0 = __shfl(x, 63);
  int y = v1;
#pragma unroll
  for (int off = 1; off < 64; off <<= 1) {
    int t = __shfl_up(y, (unsigned)off);
    if (lane >= off) y += t;
  }
  if (lane < nb) bsum[lane] = x - v0;
  if (64 + lane < nb) bsum[64 + lane] = tot0 + (y - v1);
  if (lane == 63) rowptr[n] = tot0 + y;
}

__global__ __launch_bounds__(1024) void k_scan3(int* __restrict__ rowptr,
                                                const int* __restrict__ bsum, int n) {
  int i = blockIdx.x * 1024 + threadIdx.x;
  if (i < n) rowptr[i] += bsum[blockIdx.x];
}

// ---- pass B2: place entries into csr (one bucket = one block = one XCD) ----

__global__ __launch_bounds__(256) void k_place(const int* __restrict__ gcur,
                                               const int* __restrict__ gbuf,
                                               const int* __restrict__ rowptr,
                                               int* __restrict__ csr, int n) {
  __shared__ int rp[512], hf[512];
  int b = blockIdx.x, tid = threadIdx.x;
#pragma unroll
  for (int k = 0; k < 2; ++k) {
    int i = k * 256 + tid, node = b * 512 + i;
    rp[i] = (node < n) ? rowptr[node] : 0;
    hf[i] = 0;
  }
  __syncthreads();
  int m = gcur[b];
  for (int i = tid; i < m; i += 256) {
    int ent = gbuf[(size_t)b * GCAP + i];
    int d = ent & 511, s = ent >> 9;
    csr[rp[d] + atomicAdd(&hf[d], 1)] = s;
  }
}

// ---- fp32 -> bf16 row conversion ------------------------------------------

__global__ __launch_bounds__(256) void k_tobf16(const float* __restrict__ in,
                                                short* __restrict__ ob, long long ng) {
  long long i = (long long)blockIdx.x * 256 + threadIdx.x;   // groups of 8 floats
  if (i >= ng) return;
  const float4* p = (const float4*)in + i * 2;
  float4 a = p[0], b = p[1];
  uint4 o;
  o.x = pack2(a.x, a.y); o.y = pack2(a.z, a.w);
  o.z = pack2(b.x, b.y); o.w = pack2(b.z, b.w);
  ((uint4*)ob)[i] = o;
}

// ---- weight prep: fp32 W[k][c] -> bf16 transposed WT[c][k] ----------------

__global__ __launch_bounds__(256) void k_wprep(const float* __restrict__ W0,
                                               const float* __restrict__ W1,
                                               const float* __restrict__ W2,
                                               const float* __restrict__ W3,
                                               short* __restrict__ WT) {
  const float* W = (blockIdx.y == 0) ? W0 : (blockIdx.y == 1) ? W1
                 : (blockIdx.y == 2) ? W2 : W3;
  short* o = WT + (size_t)blockIdx.y * WPANEL;
  int i = blockIdx.x * 256 + threadIdx.x;
  if (i < D * D) {
    int k = i >> 7, c = i & 127;
    o[c * WSTRIDE + k] = (short)f2bf(W[i]);
  }
}

// ---- bf16 mean aggregation: wave/node, 16-lane quarters, 4 edges in flight -

__global__ __launch_bounds__(256) void k_agg_bf(const short* __restrict__ hb,
                                                const int* __restrict__ rowptr,
                                                const int* __restrict__ csr,
                                                const float* __restrict__ inv_denom,
                                                short* __restrict__ agg, int n) {
  int gw = (int)((blockIdx.x * 256u + threadIdx.x) >> 6);
  if (gw >= n) return;
  int lane = threadIdx.x & 63;
  int q = lane >> 4, s16 = lane & 15;
  int beg = __builtin_amdgcn_readfirstlane(rowptr[gw]);
  int end = __builtin_amdgcn_readfirstlane(rowptr[gw + 1]);
  float acc[8];
#pragma unroll
  for (int k = 0; k < 8; ++k) acc[k] = 0.f;
  int e = beg + q;
  for (; e + 4 < end; e += 8) {   // 2 edges per quarter in flight
    int s0 = csr[e], s1 = csr[e + 4];
    uint4 v0 = ((const uint4*)(hb + (size_t)s0 * D))[s16];
    uint4 v1 = ((const uint4*)(hb + (size_t)s1 * D))[s16];
    acc[0] += __uint_as_float(v0.x << 16); acc[1] += __uint_as_float(v0.x & 0xffff0000u);
    acc[2] += __uint_as_float(v0.y << 16); acc[3] += __uint_as_float(v0.y & 0xffff0000u);
    acc[4] += __uint_as_float(v0.z << 16); acc[5] += __uint_as_float(v0.z & 0xffff0000u);
    acc[6] += __uint_as_float(v0.w << 16); acc[7] += __uint_as_float(v0.w & 0xffff0000u);
    acc[0] += __uint_as_float(v1.x << 16); acc[1] += __uint_as_float(v1.x & 0xffff0000u);
    acc[2] += __uint_as_float(v1.y << 16); acc[3] += __uint_as_float(v1.y & 0xffff0000u);
    acc[4] += __uint_as_float(v1.z << 16); acc[5] += __uint_as_float(v1.z & 0xffff0000u);
    acc[6] += __uint_as_float(v1.w << 16); acc[7] += __uint_as_float(v1.w & 0xffff0000u);
  }
  if (e < end) {
    int s0 = csr[e];
    uint4 v0 = ((const uint4*)(hb + (size_t)s0 * D))[s16];
    acc[0] += __uint_as_float(v0.x << 16); acc[1] += __uint_as_float(v0.x & 0xffff0000u);
    acc[2] += __uint_as_float(v0.y << 16); acc[3] += __uint_as_float(v0.y & 0xffff0000u);
    acc[4] += __uint_as_float(v0.z << 16); acc[5] += __uint_as_float(v0.z & 0xffff0000u);
    acc[6] += __uint_as_float(v0.w << 16); acc[7] += __uint_as_float(v0.w & 0xffff0000u);
  }
#pragma unroll
  for (int k = 0; k < 8; ++k) {
    acc[k] += __shfl_xor(acc[k], 16);
    acc[k] += __shfl_xor(acc[k], 32);
  }
  if (q == 0) {
    float iv = inv_denom[gw];
    uint4 o;
    o.x = pack2(acc[0] * iv, acc[1] * iv);
    o.y = pack2(acc[2] * iv, acc[3] * iv);
    o.z = pack2(acc[4] * iv, acc[5] * iv);
    o.w = pack2(acc[6] * iv, acc[7] * iv);
    ((uint4*)(agg + (size_t)gw * D))[s16] = o;
  }
}

// ---- fused layer GEMM (bf16 operands): out = relu(A@Wl + H@Wr + b) ---------
// OUTF=0: bf16 out; OUTF=1: fp32 out.

template <int OUTF>
__global__ __launch_bounds__(512) void k_fgemm_bf(const short* __restrict__ A,
                                                  const short* __restrict__ H,
                                                  const short* __restrict__ WTl,
                                                  const short* __restrict__ WTr,
                                                  const float* __restrict__ bias,
                                                  void* __restrict__ outv, int n) {
  __shared__ short wl[WPANEL];
  __shared__ short wr[WPANEL];
  int tid = threadIdx.x;
  for (int i = tid; i < WPANEL / 8; i += 512) {
    ((int4*)wl)[i] = ((const int4*)WTl)[i];
    ((int4*)wr)[i] = ((const int4*)WTr)[i];
  }
  __syncthreads();

  int lane = tid & 63, wid = tid >> 6;
  int c = lane & 15, g = lane >> 4;
  float bv[8];
#pragma unroll
  for (int cc = 0; cc < 8; ++cc) bv[cc] = bias[cc * 16 + c];

  int ntile = (n + 15) >> 4;
  for (int tile = blockIdx.x * 8 + wid; tile < ntile; tile += gridDim.x * 8) {
    int r0 = tile * 16;
    int row = r0 + c;
    bool rok = row < n;
    f32x4 acc[8];
#pragma unroll
    for (int cc = 0; cc < 8; ++cc) acc[cc] = (f32x4){0.f, 0.f, 0.f, 0.f};

#pragma unroll
    for (int t = 0; t < 4; ++t) {
      short8v af = (short8v){0,0,0,0,0,0,0,0};
      short8v hf = (short8v){0,0,0,0,0,0,0,0};
      if (rok) {
        af = *(const short8v*)(A + (size_t)row * D + t * 32 + g * 8);
        hf = *(const short8v*)(H + (size_t)row * D + t * 32 + g * 8);
      }
      int kb = t * 32 + g * 8;
#pragma unroll
      for (int cc = 0; cc < 8; ++cc) {
        short8v bl = *(const short8v*)&wl[(cc * 16 + c) * WSTRIDE + kb];
        acc[cc] = __builtin_amdgcn_mfma_f32_16x16x32_bf16(af, bl, acc[cc], 0, 0, 0);
        short8v br = *(const short8v*)&wr[(cc * 16 + c) * WSTRIDE + kb];
        acc[cc] = __builtin_amdgcn_mfma_f32_16x16x32_bf16(hf, br, acc[cc], 0, 0, 0);
      }
    }
#pragma unroll
    for (int cc = 0; cc < 8; ++cc) {
#pragma unroll
      for (int i = 0; i < 4; ++i) {
        int rr = r0 + g * 4 + i;
        if (rr < n) {
          float o = acc[cc][i] + bv[cc];
          o = o > 0.f ? o : 0.f;
          if (OUTF) ((float*)outv)[(size_t)rr * D + cc * 16 + c] = o;
          else ((short*)outv)[(size_t)rr * D + cc * 16 + c] = (short)f2bf(o);
        }
      }
    }
  }
}

// ---- fp32 fallback kernels (used only if ws_size is too small) -------------

__global__ __launch_bounds__(256) void k_agg_f32(const float* __restrict__ h,
                                                 const int* __restrict__ rowptr,
                                                 const int* __restrict__ csr,
                                                 const float* __restrict__ inv_denom,
                                                 float* __restrict__ agg, int n) {
  int gw = (int)((blockIdx.x * 256u + threadIdx.x) >> 6);
  if (gw >= n) return;
  int lane = threadIdx.x & 63;
  int half = lane >> 5, sub = lane & 31;
  int beg = __builtin_amdgcn_readfirstlane(rowptr[gw]);
  int end = __builtin_amdgcn_readfirstlane(rowptr[gw + 1]);
  float sx0 = 0.f, sy0 = 0.f, sz0 = 0.f, sw0 = 0.f;
  float sx1 = 0.f, sy1 = 0.f, sz1 = 0.f, sw1 = 0.f;
  int e = beg;
  for (; e + 4 <= end; e += 4) {
    int i0 = csr[e + half];
    int i1 = csr[e + 2 + half];
    float4 v0 = ((const float4*)(h + (size_t)i0 * D))[sub];
    float4 v1 = ((const float4*)(h + (size_t)i1 * D))[sub];
    sx0 += v0.x; sy0 += v0.y; sz0 += v0.z; sw0 += v0.w;
    sx1 += v1.x; sy1 += v1.y; sz1 += v1.z; sw1 += v1.w;
  }
  if (e + 2 <= end) {
    int i0 = csr[e + half];
    float4 v0 = ((const float4*)(h + (size_t)i0 * D))[sub];
    sx0 += v0.x; sy0 += v0.y; sz0 += v0.z; sw0 += v0.w;
    e += 2;
  }
  if (e < end) {
    int i0 = csr[e];
    float4 v0 = ((const float4*)(h + (size_t)i0 * D))[sub];
    if (half == 0) { sx0 += v0.x; sy0 += v0.y; sz0 += v0.z; sw0 += v0.w; }
  }
  float sx = sx0 + sx1, sy = sy0 + sy1, sz = sz0 + sz1, sw = sw0 + sw1;
  sx += __shfl_xor(sx, 32); sy += __shfl_xor(sy, 32);
  sz += __shfl_xor(sz, 32); sw += __shfl_xor(sw, 32);
  if (half == 0) {
    float iv = inv_denom[gw];
    float4 r; r.x = sx * iv; r.y = sy * iv; r.z = sz * iv; r.w = sw * iv;
    ((float4*)(agg + (size_t)gw * D))[sub] = r;
  }
}

__global__ __launch_bounds__(512) void k_fgemm_f32(const float* A, const float* H,
                                                   const short* __restrict__ WTl,
                                                   const short* __restrict__ WTr,
                                                   const float* __restrict__ bias,
                                                   float* out, int n) {
  __shared__ short wl[WPANEL];
  __shared__ short wr[WPANEL];
  int tid = threadIdx.x;
  for (int i = tid; i < WPANEL / 8; i += 512) {
    ((int4*)wl)[i] = ((const int4*)WTl)[i];
    ((int4*)wr)[i] = ((const int4*)WTr)[i];
  }
  __syncthreads();
  int lane = tid & 63, wid = tid >> 6;
  int c = lane & 15, g = lane >> 4;
  float bv[8];
#pragma unroll
  for (int cc = 0; cc < 8; ++cc) bv[cc] = bias[cc * 16 + c];
  int ntile = (n + 15) >> 4;
  for (int tile = blockIdx.x * 8 + wid; tile < ntile; tile += gridDim.x * 8) {
    int r0 = tile * 16;
    int row = r0 + c;
    bool rok = row < n;
    f32x4 acc[8];
#pragma unroll
    for (int cc = 0; cc < 8; ++cc) acc[cc] = (f32x4){0.f, 0.f, 0.f, 0.f};
#pragma unroll
    for (int t = 0; t < 4; ++t) {
      short8v af = (short8v){0,0,0,0,0,0,0,0};
      short8v hf = (short8v){0,0,0,0,0,0,0,0};
      if (rok) {
        const float4* pa = (const float4*)(A + (size_t)row * D + t * 32 + g * 8);
        float4 a0 = pa[0], a1 = pa[1];
        const float4* ph = (const float4*)(H + (size_t)row * D + t * 32 + g * 8);
        float4 h0 = ph[0], h1 = ph[1];
        af[0] = (short)f2bf(a0.x); af[1] = (short)f2bf(a0.y); af[2] = (short)f2bf(a0.z); af[3] = (short)f2bf(a0.w);
        af[4] = (short)f2bf(a1.x); af[5] = (short)f2bf(a1.y); af[6] = (short)f2bf(a1.z); af[7] = (short)f2bf(a1.w);
        hf[0] = (short)f2bf(h0.x); hf[1] = (short)f2bf(h0.y); hf[2] = (short)f2bf(h0.z); hf[3] = (short)f2bf(h0.w);
        hf[4] = (short)f2bf(h1.x); hf[5] = (short)f2bf(h1.y); hf[6] = (short)f2bf(h1.z); hf[7] = (short)f2bf(h1.w);
      }
      int kb = t * 32 + g * 8;
#pragma unroll
      for (int cc = 0; cc < 8; ++cc) {
        short8v bl = *(const short8v*)&wl[(cc * 16 + c) * WSTRIDE + kb];
        acc[cc] = __builtin_amdgcn_mfma_f32_16x16x32_bf16(af, bl, acc[cc], 0, 0, 0);
        short8v br = *(const short8v*)&wr[(cc * 16 + c) * WSTRIDE + kb];
        acc[cc] = __builtin_amdgcn_mfma_f32_16x16x32_bf16(hf, br, acc[cc], 0, 0, 0);
      }
    }
#pragma unroll
    for (int cc = 0; cc < 8; ++cc) {
#pragma unroll
      for (int i = 0; i < 4; ++i) {
        int rr = r0 + g * 4 + i;
        if (rr < n) {
          float o = acc[cc][i] + bv[cc];
          out[(size_t)rr * D + cc * 16 + c] = o > 0.f ? o : 0.f;
        }
      }
    }
  }
}

// ---- launch ----------------------------------------------------------------

extern "C" void kernel_launch(void* const* d_in, const int* in_sizes, int n_in,
                              void* d_out, int out_size, void* d_ws, size_t ws_size,
                              hipStream_t stream) {
  const float* x   = (const float*)d_in[0];
  const int*   ei  = (const int*)d_in[1];
  const float* Wl0 = (const float*)d_in[2];
  const float* Wr0 = (const float*)d_in[3];
  const float* b0  = (const float*)d_in[4];
  const float* Wl1 = (const float*)d_in[5];
  const float* Wr1 = (const float*)d_in[6];
  const float* b1  = (const float*)d_in[7];
  const int N = in_sizes[0] / D;
  const int E = in_sizes[1] / 2;
  float* out = (float*)d_out;

  size_t NP = ((size_t)N + 64) & ~(size_t)63;
  size_t EP = ((size_t)E + 63) & ~(size_t)63;
  const int NBUCK = (N + 511) >> 9;

  int* W = (int*)d_ws;
  size_t off = 0;
  int*   rowptr = W + off; off += NP;
  int*   cnt    = W + off; off += NP;
  float* inv    = (float*)(W + off); off += NP;
  int*   bsum   = W + off; off += 1024;
  int*   gcur   = W + off; off += 256;
  int*   csr    = W + off; off += EP;
  short* wt     = (short*)(W + off); off += (size_t)4 * WPANEL / 2;
  size_t base = off;
  short* aggb = (short*)(W + off); off += NP * 64;
  short* xb   = (short*)(W + off); off += NP * 64;
  short* h1b  = (short*)(W + off); off += NP * 64;
  size_t need_new = off * 4;
  float* aggf = (float*)(W + base);                 // fallback fp32 agg buffer
  bool use_bf = ws_size >= need_new;
  int* gbuf = use_bf ? (int*)xb : (int*)aggf;       // overlay: consumed pre-agg

  hipMemsetAsync(gcur, 0, 256 * sizeof(int), stream);

  int NB = (N + 1023) / 1024;
  k_bin<<<(E + 2047) / 2048, 256, 0, stream>>>(ei, E, gcur, gbuf);
  k_hist<<<NBUCK, 256, 0, stream>>>(gcur, gbuf, cnt, N);
  k_scan1<<<NB, 1024, 0, stream>>>(cnt, N, rowptr, inv, bsum);
  k_scan2<<<1, 64, 0, stream>>>(bsum, NB, rowptr, N);
  k_scan3<<<NB, 1024, 0, stream>>>(rowptr, bsum, N);
  k_place<<<NBUCK, 256, 0, stream>>>(gcur, gbuf, rowptr, csr, N);

  dim3 wgrid((D * D + 255) / 256, 4);
  k_wprep<<<wgrid, 256, 0, stream>>>(Wl0, Wr0, Wl1, Wr1, wt);

  int agrid = (N + 3) / 4;

  if (use_bf) {
    long long ng = (long long)N * (D / 8);
    k_tobf16<<<(int)((ng + 255) / 256), 256, 0, stream>>>(x, xb, ng);
    // layer 0
    k_agg_bf<<<agrid, 256, 0, stream>>>(xb, rowptr, csr, inv, aggb, N);
    k_fgemm_bf<0><<<512, 512, 0, stream>>>(aggb, xb, wt, wt + WPANEL, b0, h1b, N);
    // layer 1
    k_agg_bf<<<agrid, 256, 0, stream>>>(h1b, rowptr, csr, inv, aggb, N);
    k_fgemm_bf<1><<<512, 512, 0, stream>>>(aggb, h1b, wt + 2 * WPANEL, wt + 3 * WPANEL, b1, out, N);
  } else {
    // fp32 fallback (proven footprint)
    k_agg_f32<<<agrid, 256, 0, stream>>>(x, rowptr, csr, inv, aggf, N);
    k_fgemm_f32<<<512, 512, 0, stream>>>(aggf, x, wt, wt + WPANEL, b0, out, N);
    k_agg_f32<<<agrid, 256, 0, stream>>>(out, rowptr, csr, inv, aggf, N);
    k_fgemm_f32<<<512, 512, 0, stream>>>(aggf, out, wt + 2 * WPANEL, wt + 3 * WPANEL, b1, out, N);
  }
}